// Round 8
// baseline (190.156 us; speedup 1.0000x reference)
//
#include <hip/hip_runtime.h>

#define D 256
#define D4 (D/4)        // 64 float4 per fp32 row
#define RELQW 192       // u32 words per int8 relation block (u0,u1,re rows)
#define PARW 8          // floats per relation in par_buf

#define QSCALE (1.0f/254.0f)   // fixed int8 step (same as verified int8 version)
#define QINV   254.0f
#define QS2    (QSCALE*QSCALE)

// native clang vector type: required by __builtin_nontemporal_load
typedef int v4i __attribute__((ext_vector_type(4)));
union V4 { v4i v; int4 i; };

__device__ inline float dot4(const float4 u, const float4 v) {
    return u.x*v.x + u.y*v.y + u.z*v.z + u.w*v.w;
}

__device__ inline float wsum(float v) {
    #pragma unroll
    for (int off = 32; off > 0; off >>= 1)
        v += __shfl_xor(v, off, 64);
    return v;
}

__device__ inline int q8(float v) {
    float q = rintf(v * QINV);
    q = fmaxf(-127.f, fminf(127.f, q));
    return (int)q;
}

__device__ inline unsigned pack_i(const int* q) {
    return (unsigned)(q[0] & 255)
         | ((unsigned)(q[1] & 255) << 8)
         | ((unsigned)(q[2] & 255) << 16)
         | ((unsigned)(q[3] & 255) << 24);
}

__device__ inline unsigned pack4q(float a, float b, float c, float d) {
    int q[4] = {q8(a), q8(b), q8(c), q8(d)};
    return pack_i(q);
}

// nontemporal 16B load of an int8-row chunk (single global_load_dwordx4 nt)
__device__ inline int4 nt_load16(const int4* p) {
    V4 u;
    u.v = __builtin_nontemporal_load((const v4i*)p);
    return u.i;
}

// packed int8 dot: c += dot(a_bytes, b_bytes). v_dot4_i32_i8 on gfx9+/CDNA.
#if __has_builtin(__builtin_amdgcn_sdot4)
__device__ inline int sdot4(int a, int b, int c) {
    return __builtin_amdgcn_sdot4(a, b, c, false);
}
#else
__device__ inline int sdot4(int a, int b, int c) {
    #pragma unroll
    for (int j = 0; j < 4; ++j) {
        int av = (int)(((unsigned)a) << (24 - 8*j)) >> 24;
        int bv = (int)(((unsigned)b) << (24 - 8*j)) >> 24;
        c += av * bv;
    }
    return c;
}
#endif

// ---- merged prep: waves [0,E) quantize ent rows; waves [E,E+R) rel pre ---
// (unchanged from round-5 verified version, absmax 0.03125)
__global__ __launch_bounds__(256) void transint_prep(
    const float*  __restrict__ ent,       // [E, D] fp32
    const float*  __restrict__ heads,
    const float*  __restrict__ bases,
    const int*    __restrict__ rel2head,
    const float*  __restrict__ rel2mult,
    unsigned*     __restrict__ ent_q,     // [E, 64] u32 (4 int8 each)
    unsigned*     __restrict__ rel_q,     // [R, 192] int8 rows u0,u1,re
    float*        __restrict__ par_buf,   // [R, 8]
    int E, int R)
{
    const int wave = (blockIdx.x * blockDim.x + threadIdx.x) >> 6;
    const int lane = threadIdx.x & 63;

    if (wave < E) {
        float4 v = ((const float4*)ent)[(size_t)wave * D4 + lane];
        ent_q[(size_t)wave * 64 + lane] = pack4q(v.x, v.y, v.z, v.w);
        return;
    }
    const int r = wave - E;
    if (r >= R) return;

    const int   hd   = rel2head[r];
    const float mult = rel2mult[r];
    const float4* hrow = (const float4*)(heads + (size_t)hd * D);
    const float4* arow = (const float4*)(bases + (size_t)r * 2 * D);

    float4 a0 = arow[lane];
    float4 a1 = arow[D4 + lane];
    float4 re = hrow[lane];
    re.x *= mult; re.y *= mult; re.z *= mult; re.w *= mult;

    float aa = wsum(dot4(a0, a0));
    float ab = wsum(dot4(a0, a1));
    float dd = wsum(dot4(a1, a1));

    float det = aa * dd - ab * ab;
    float m00, m01, m11;
    if (det != 0.0f) {
        float inv = 1.0f / det;
        m00 = dd * inv; m01 = -ab * inv; m11 = aa * inv;
    } else {
        float inv = 1.0f / aa;
        m00 = inv; m01 = 0.0f; m11 = inv;
    }
    // Q = 2M - M*(ATA*M)
    float t00 = aa * m00 + ab * m01;
    float t01 = aa * m01 + ab * m11;
    float t10 = ab * m00 + dd * m01;
    float t11 = ab * m01 + dd * m11;
    float q00 = 2.f * m00 - (m00 * t00 + m01 * t10);
    float q01 = 2.f * m01 - (m00 * t01 + m01 * t11);
    float q11 = 2.f * m11 - (m01 * t01 + m11 * t11);

    // Gram-Schmidt: a0 = c00 u0 ; a1 = c10 u0 + c11 u1
    float c00  = sqrtf(aa);
    float ic00 = (c00 > 0.f) ? 1.f / c00 : 0.f;
    float4 u0;
    u0.x = a0.x * ic00; u0.y = a0.y * ic00; u0.z = a0.z * ic00; u0.w = a0.w * ic00;
    float c10 = ab * ic00;
    float4 v;
    v.x = a1.x - c10 * u0.x; v.y = a1.y - c10 * u0.y;
    v.z = a1.z - c10 * u0.z; v.w = a1.w - c10 * u0.w;
    float vv   = wsum(dot4(v, v));
    float c11  = sqrtf(vv);
    float ic11 = (c11 > 0.f) ? 1.f / c11 : 0.f;
    float4 u1;
    u1.x = v.x * ic11; u1.y = v.y * ic11; u1.z = v.z * ic11; u1.w = v.w * ic11;

    // S = C^T Q C, C = [[c00,0],[c10,c11]]
    float s00 = c00*c00*q00 + 2.f*c00*c10*q01 + c10*c10*q11;
    float s01 = c00*c11*q01 + c10*c11*q11;
    float s11 = c11*c11*q11;

    // quantize rows; keep int values for the precomputed quantized dots
    int qa[4] = {q8(u0.x), q8(u0.y), q8(u0.z), q8(u0.w)};
    int qb[4] = {q8(u1.x), q8(u1.y), q8(u1.z), q8(u1.w)};
    int qr[4] = {q8(re.x), q8(re.y), q8(re.z), q8(re.w)};

    unsigned* basep = rel_q + (size_t)r * RELQW;
    basep[lane]       = pack_i(qa);
    basep[64 + lane]  = pack_i(qb);
    basep[128 + lane] = pack_i(qr);

    // quantized-domain dots (exact: wave sums < 2^24, exact in fp32)
    float du0re = wsum((float)(qa[0]*qr[0] + qa[1]*qr[1] + qa[2]*qr[2] + qa[3]*qr[3]));
    float du1re = wsum((float)(qb[0]*qr[0] + qb[1]*qr[1] + qb[2]*qr[2] + qb[3]*qr[3]));
    float drere = wsum((float)(qr[0]*qr[0] + qr[1]*qr[1] + qr[2]*qr[2] + qr[3]*qr[3]));

    if (lane == 0) {
        float* p = par_buf + (size_t)r * PARW;
        p[0] = s00; p[1] = s01; p[2] = s11;
        p[3] = du0re * QS2;   // u0 . re
        p[4] = du1re * QS2;   // u1 . re
        p[5] = drere * QS2;   // re . re
        p[6] = 0.f; p[7] = 0.f;
    }
}

// ---- main: int8 gather + sdot4 expanded form, 8 samples/wave ------------
// CHANGE vs round 5 (numerics identical): the 8 entity-row gathers use
// nontemporal loads (nt flag, no L2 allocation) via a native ext_vector
// type (HIP int4 is rejected by the builtin). The 67 MB entity miss
// stream no longer evicts the 768-KB relation table from L2, so ~50 MB
// of relation gathers become L2 hits instead of riding the capped
// L1/L2-miss request path.
__global__ __launch_bounds__(256) void transint_main(
    const int*      __restrict__ pos_h,
    const int*      __restrict__ pos_t,
    const int*      __restrict__ pos_r,
    const int*      __restrict__ neg_h,
    const int*      __restrict__ neg_t,
    const unsigned* __restrict__ ent_q,     // [E, 64] int8 rows
    const unsigned* __restrict__ rel_q,     // [R, 192] int8 rows
    const float*    __restrict__ par_buf,   // [R, 8]
    float*          __restrict__ out,       // [2*B]
    int nB)
{
    const int wave = (blockIdx.x * blockDim.x + threadIdx.x) >> 6;
    const int lane = threadIdx.x & 63;
    const int g    = lane >> 4;
    const int gl   = lane & 15;
    const int base = wave * 8;
    int bs[2];
    bs[0] = base + g;
    bs[1] = base + 4 + g;
    if (bs[0] >= nB) return;
    const bool has1 = (bs[1] < nB);
    if (!has1) bs[1] = bs[0];

    const int4* eq = (const int4*)ent_q;     // 16 int4 chunks per ent row
    const int4* rq = (const int4*)rel_q;     // 48 int4 chunks per relation

    int rr[2];
    int4 qh[2], qt[2], qx[2], qy[2], qu0[2], qu1[2], qre[2];

    #pragma unroll
    for (int s = 0; s < 2; ++s) {
        const int b = bs[s];
        rr[s] = pos_r[b];
        // entity rows: non-temporal (bypass L2 allocation)
        qh[s] = nt_load16(eq + (size_t)pos_h[b] * 16 + gl);
        qt[s] = nt_load16(eq + (size_t)pos_t[b] * 16 + gl);
        qx[s] = nt_load16(eq + (size_t)neg_h[b] * 16 + gl);
        qy[s] = nt_load16(eq + (size_t)neg_t[b] * 16 + gl);
        // relation rows: temporal (small table, keep L2-resident)
        const int4* rb = rq + (size_t)rr[s] * 48;
        qu0[s] = rb[gl];
        qu1[s] = rb[gl + 16];
        qre[s] = rb[gl + 32];
    }

    int p0[2], p1[2], sp[2], n0[2], n1[2], sn[2];

    #pragma unroll
    for (int s = 0; s < 2; ++s) {
        int u0h=0,u0t=0,u1h=0,u1t=0, hh=0,tt=0,ht=0, hre=0,tre=0;
        int u0x=0,u0y=0,u1x=0,u1y=0, xx=0,yy=0,xy=0, xre=0,yre=0;

        const int* hw  = (const int*)&qh[s];
        const int* tw  = (const int*)&qt[s];
        const int* xw  = (const int*)&qx[s];
        const int* yw  = (const int*)&qy[s];
        const int* aw  = (const int*)&qu0[s];
        const int* bw  = (const int*)&qu1[s];
        const int* rw  = (const int*)&qre[s];

        #pragma unroll
        for (int w = 0; w < 4; ++w) {
            const int h = hw[w], t = tw[w], x = xw[w], y = yw[w];
            const int a = aw[w], b2 = bw[w], r2 = rw[w];
            u0h = sdot4(a,  h, u0h);  u0t = sdot4(a,  t, u0t);
            u1h = sdot4(b2, h, u1h);  u1t = sdot4(b2, t, u1t);
            hh  = sdot4(h,  h, hh);   tt  = sdot4(t,  t, tt);
            ht  = sdot4(h,  t, ht);
            hre = sdot4(h, r2, hre);  tre = sdot4(t, r2, tre);
            u0x = sdot4(a,  x, u0x);  u0y = sdot4(a,  y, u0y);
            u1x = sdot4(b2, x, u1x);  u1y = sdot4(b2, y, u1y);
            xx  = sdot4(x,  x, xx);   yy  = sdot4(y,  y, yy);
            xy  = sdot4(x,  y, xy);
            xre = sdot4(x, r2, xre);  yre = sdot4(y, r2, yre);
        }
        p0[s] = u0h - u0t;
        p1[s] = u1h - u1t;
        sp[s] = hh + tt - 2*ht + 2*hre - 2*tre;
        n0[s] = u0x - u0y;
        n1[s] = u1x - u1y;
        sn[s] = xx + yy - 2*xy + 2*xre - 2*yre;
    }

    // 4-stage butterfly within the 16-lane group (exact int adds)
    #pragma unroll
    for (int off = 8; off > 0; off >>= 1) {
        #pragma unroll
        for (int s = 0; s < 2; ++s) {
            p0[s] += __shfl_xor(p0[s], off, 64);
            p1[s] += __shfl_xor(p1[s], off, 64);
            sp[s] += __shfl_xor(sp[s], off, 64);
            n0[s] += __shfl_xor(n0[s], off, 64);
            n1[s] += __shfl_xor(n1[s], off, 64);
            sn[s] += __shfl_xor(sn[s], off, 64);
        }
    }

    if (gl == 0) {
        #pragma unroll
        for (int s = 0; s < 2; ++s) {
            if (s == 1 && !has1) break;
            const float* par = par_buf + (size_t)rr[s] * PARW;
            const float s00 = par[0], s01 = par[1], s11 = par[2];
            const float u0re = par[3], u1re = par[4], rere = par[5];
            float P0 = (float)p0[s] * QS2 + u0re;
            float P1 = (float)p1[s] * QS2 + u1re;
            float SP = (float)sp[s] * QS2 + rere;
            float N0 = (float)n0[s] * QS2 + u0re;
            float N1 = (float)n1[s] * QS2 + u1re;
            float SN = (float)sn[s] * QS2 + rere;
            out[bs[s]]      = SP - (s00*P0*P0 + 2.f*s01*P0*P1 + s11*P1*P1);
            out[nB + bs[s]] = SN - (s00*N0*N0 + 2.f*s01*N0*N1 + s11*N1*N1);
        }
    }
}

extern "C" void kernel_launch(void* const* d_in, const int* in_sizes, int n_in,
                              void* d_out, int out_size, void* d_ws, size_t ws_size,
                              hipStream_t stream) {
    const int*   pos_h    = (const int*)  d_in[0];
    const int*   pos_t    = (const int*)  d_in[1];
    const int*   pos_r    = (const int*)  d_in[2];
    const int*   neg_h    = (const int*)  d_in[3];
    const int*   neg_t    = (const int*)  d_in[4];
    // d_in[5] = neg_r (unused by reference scores)
    const float* ent_emb  = (const float*)d_in[6];
    const float* heads    = (const float*)d_in[7];
    const float* bases    = (const float*)d_in[8];
    const int*   rel2head = (const int*)  d_in[9];
    const float* rel2mult = (const float*)d_in[10];
    float* out = (float*)d_out;

    const int nB = in_sizes[0];               // 65536
    const int R  = in_sizes[9];               // 1000
    const int E  = in_sizes[6] / D;           // 100000

    // ws layout: ent_q (E*256 B) | rel_q (R*768 B) | par (R*32 B)
    unsigned* ent_q   = (unsigned*)d_ws;
    unsigned* rel_q   = (unsigned*)((char*)d_ws + (size_t)E * 256);
    float*    par_buf = (float*)(rel_q + (size_t)R * RELQW);

    // merged prep: E quant waves + R rel waves
    {
        int waves = E + R;
        dim3 grid((waves + 3) / 4);
        transint_prep<<<grid, dim3(256), 0, stream>>>(
            ent_emb, heads, bases, rel2head, rel2mult,
            ent_q, rel_q, par_buf, E, R);
    }
    // main: 8 samples/wave, 32 per 256-thread block
    {
        dim3 grid((nB + 31) / 32);
        transint_main<<<grid, dim3(256), 0, stream>>>(
            pos_h, pos_t, pos_r, neg_h, neg_t,
            ent_q, rel_q, par_buf, out, nB);
    }
}

// Round 9
// 186.400 us; speedup vs baseline: 1.0202x; 1.0202x over previous
//
#include <hip/hip_runtime.h>

#define D 256
#define D4 (D/4)        // 64 float4 per fp32 row
#define RELQW 192       // u32 words per int8 relation block (u0,u1,re rows)
#define PARW 8          // floats per relation in par_buf

#define QSCALE (1.0f/254.0f)   // fixed int8 step (same as verified int8 version)
#define QINV   254.0f
#define QS2    (QSCALE*QSCALE)

__device__ inline float dot4(const float4 u, const float4 v) {
    return u.x*v.x + u.y*v.y + u.z*v.z + u.w*v.w;
}

__device__ inline float wsum(float v) {
    #pragma unroll
    for (int off = 32; off > 0; off >>= 1)
        v += __shfl_xor(v, off, 64);
    return v;
}

__device__ inline int q8(float v) {
    float q = rintf(v * QINV);
    q = fmaxf(-127.f, fminf(127.f, q));
    return (int)q;
}

__device__ inline unsigned pack_i(const int* q) {
    return (unsigned)(q[0] & 255)
         | ((unsigned)(q[1] & 255) << 8)
         | ((unsigned)(q[2] & 255) << 16)
         | ((unsigned)(q[3] & 255) << 24);
}

__device__ inline unsigned pack4q(float a, float b, float c, float d) {
    int q[4] = {q8(a), q8(b), q8(c), q8(d)};
    return pack_i(q);
}

// packed int8 dot: c += dot(a_bytes, b_bytes). v_dot4_i32_i8 on gfx9+/CDNA.
#if __has_builtin(__builtin_amdgcn_sdot4)
__device__ inline int sdot4(int a, int b, int c) {
    return __builtin_amdgcn_sdot4(a, b, c, false);
}
#else
__device__ inline int sdot4(int a, int b, int c) {
    #pragma unroll
    for (int j = 0; j < 4; ++j) {
        int av = (int)(((unsigned)a) << (24 - 8*j)) >> 24;
        int bv = (int)(((unsigned)b) << (24 - 8*j)) >> 24;
        c += av * bv;
    }
    return c;
}
#endif

// ---- merged prep: waves [0,E) quantize ent rows; waves [E,E+R) rel pre ---
// (round-5 verified version, absmax 0.03125; compulsory-traffic-bound)
__global__ __launch_bounds__(256) void transint_prep(
    const float*  __restrict__ ent,       // [E, D] fp32
    const float*  __restrict__ heads,
    const float*  __restrict__ bases,
    const int*    __restrict__ rel2head,
    const float*  __restrict__ rel2mult,
    unsigned*     __restrict__ ent_q,     // [E, 64] u32 (4 int8 each)
    unsigned*     __restrict__ rel_q,     // [R, 192] int8 rows u0,u1,re
    float*        __restrict__ par_buf,   // [R, 8]
    int E, int R)
{
    const int wave = (blockIdx.x * blockDim.x + threadIdx.x) >> 6;
    const int lane = threadIdx.x & 63;

    if (wave < E) {
        float4 v = ((const float4*)ent)[(size_t)wave * D4 + lane];
        ent_q[(size_t)wave * 64 + lane] = pack4q(v.x, v.y, v.z, v.w);
        return;
    }
    const int r = wave - E;
    if (r >= R) return;

    const int   hd   = rel2head[r];
    const float mult = rel2mult[r];
    const float4* hrow = (const float4*)(heads + (size_t)hd * D);
    const float4* arow = (const float4*)(bases + (size_t)r * 2 * D);

    float4 a0 = arow[lane];
    float4 a1 = arow[D4 + lane];
    float4 re = hrow[lane];
    re.x *= mult; re.y *= mult; re.z *= mult; re.w *= mult;

    float aa = wsum(dot4(a0, a0));
    float ab = wsum(dot4(a0, a1));
    float dd = wsum(dot4(a1, a1));

    float det = aa * dd - ab * ab;
    float m00, m01, m11;
    if (det != 0.0f) {
        float inv = 1.0f / det;
        m00 = dd * inv; m01 = -ab * inv; m11 = aa * inv;
    } else {
        float inv = 1.0f / aa;
        m00 = inv; m01 = 0.0f; m11 = inv;
    }
    // Q = 2M - M*(ATA*M)
    float t00 = aa * m00 + ab * m01;
    float t01 = aa * m01 + ab * m11;
    float t10 = ab * m00 + dd * m01;
    float t11 = ab * m01 + dd * m11;
    float q00 = 2.f * m00 - (m00 * t00 + m01 * t10);
    float q01 = 2.f * m01 - (m00 * t01 + m01 * t11);
    float q11 = 2.f * m11 - (m01 * t01 + m11 * t11);

    // Gram-Schmidt: a0 = c00 u0 ; a1 = c10 u0 + c11 u1
    float c00  = sqrtf(aa);
    float ic00 = (c00 > 0.f) ? 1.f / c00 : 0.f;
    float4 u0;
    u0.x = a0.x * ic00; u0.y = a0.y * ic00; u0.z = a0.z * ic00; u0.w = a0.w * ic00;
    float c10 = ab * ic00;
    float4 v;
    v.x = a1.x - c10 * u0.x; v.y = a1.y - c10 * u0.y;
    v.z = a1.z - c10 * u0.z; v.w = a1.w - c10 * u0.w;
    float vv   = wsum(dot4(v, v));
    float c11  = sqrtf(vv);
    float ic11 = (c11 > 0.f) ? 1.f / c11 : 0.f;
    float4 u1;
    u1.x = v.x * ic11; u1.y = v.y * ic11; u1.z = v.z * ic11; u1.w = v.w * ic11;

    // S = C^T Q C, C = [[c00,0],[c10,c11]]
    float s00 = c00*c00*q00 + 2.f*c00*c10*q01 + c10*c10*q11;
    float s01 = c00*c11*q01 + c10*c11*q11;
    float s11 = c11*c11*q11;

    // quantize rows; keep int values for the precomputed quantized dots
    int qa[4] = {q8(u0.x), q8(u0.y), q8(u0.z), q8(u0.w)};
    int qb[4] = {q8(u1.x), q8(u1.y), q8(u1.z), q8(u1.w)};
    int qr[4] = {q8(re.x), q8(re.y), q8(re.z), q8(re.w)};

    unsigned* basep = rel_q + (size_t)r * RELQW;
    basep[lane]       = pack_i(qa);
    basep[64 + lane]  = pack_i(qb);
    basep[128 + lane] = pack_i(qr);

    // quantized-domain dots (exact: wave sums < 2^24, exact in fp32)
    float du0re = wsum((float)(qa[0]*qr[0] + qa[1]*qr[1] + qa[2]*qr[2] + qa[3]*qr[3]));
    float du1re = wsum((float)(qb[0]*qr[0] + qb[1]*qr[1] + qb[2]*qr[2] + qb[3]*qr[3]));
    float drere = wsum((float)(qr[0]*qr[0] + qr[1]*qr[1] + qr[2]*qr[2] + qr[3]*qr[3]));

    if (lane == 0) {
        float* p = par_buf + (size_t)r * PARW;
        p[0] = s00; p[1] = s01; p[2] = s11;
        p[3] = du0re * QS2;   // u0 . re
        p[4] = du1re * QS2;   // u1 . re
        p[5] = drere * QS2;   // re . re
        p[6] = 0.f; p[7] = 0.f;
    }
}

// ---- main: int8 gather + sdot4 expanded form, 8 samples/wave ------------
// Exact round-5 best (186.7 us). Plain temporal loads: nt (round 8)
// regressed -3.5 us (forfeits incidental L1/L2 entity hits); sched_barrier
// + VGPR headroom (round 6) was null. The gather path is structurally
// capped; bytes are minimal at int8.
__global__ __launch_bounds__(256) void transint_main(
    const int*      __restrict__ pos_h,
    const int*      __restrict__ pos_t,
    const int*      __restrict__ pos_r,
    const int*      __restrict__ neg_h,
    const int*      __restrict__ neg_t,
    const unsigned* __restrict__ ent_q,     // [E, 64] int8 rows
    const unsigned* __restrict__ rel_q,     // [R, 192] int8 rows
    const float*    __restrict__ par_buf,   // [R, 8]
    float*          __restrict__ out,       // [2*B]
    int nB)
{
    const int wave = (blockIdx.x * blockDim.x + threadIdx.x) >> 6;
    const int lane = threadIdx.x & 63;
    const int g    = lane >> 4;
    const int gl   = lane & 15;
    const int base = wave * 8;
    int bs[2];
    bs[0] = base + g;
    bs[1] = base + 4 + g;
    if (bs[0] >= nB) return;
    const bool has1 = (bs[1] < nB);
    if (!has1) bs[1] = bs[0];

    const int4* eq = (const int4*)ent_q;     // 16 int4 chunks per ent row
    const int4* rq = (const int4*)rel_q;     // 48 int4 chunks per relation

    int rr[2];
    int4 qh[2], qt[2], qx[2], qy[2], qu0[2], qu1[2], qre[2];

    #pragma unroll
    for (int s = 0; s < 2; ++s) {
        const int b = bs[s];
        rr[s] = pos_r[b];
        qh[s] = eq[(size_t)pos_h[b] * 16 + gl];
        qt[s] = eq[(size_t)pos_t[b] * 16 + gl];
        qx[s] = eq[(size_t)neg_h[b] * 16 + gl];
        qy[s] = eq[(size_t)neg_t[b] * 16 + gl];
        const int4* rb = rq + (size_t)rr[s] * 48;
        qu0[s] = rb[gl];
        qu1[s] = rb[gl + 16];
        qre[s] = rb[gl + 32];
    }

    int p0[2], p1[2], sp[2], n0[2], n1[2], sn[2];

    #pragma unroll
    for (int s = 0; s < 2; ++s) {
        int u0h=0,u0t=0,u1h=0,u1t=0, hh=0,tt=0,ht=0, hre=0,tre=0;
        int u0x=0,u0y=0,u1x=0,u1y=0, xx=0,yy=0,xy=0, xre=0,yre=0;

        const int* hw  = (const int*)&qh[s];
        const int* tw  = (const int*)&qt[s];
        const int* xw  = (const int*)&qx[s];
        const int* yw  = (const int*)&qy[s];
        const int* aw  = (const int*)&qu0[s];
        const int* bw  = (const int*)&qu1[s];
        const int* rw  = (const int*)&qre[s];

        #pragma unroll
        for (int w = 0; w < 4; ++w) {
            const int h = hw[w], t = tw[w], x = xw[w], y = yw[w];
            const int a = aw[w], b2 = bw[w], r2 = rw[w];
            u0h = sdot4(a,  h, u0h);  u0t = sdot4(a,  t, u0t);
            u1h = sdot4(b2, h, u1h);  u1t = sdot4(b2, t, u1t);
            hh  = sdot4(h,  h, hh);   tt  = sdot4(t,  t, tt);
            ht  = sdot4(h,  t, ht);
            hre = sdot4(h, r2, hre);  tre = sdot4(t, r2, tre);
            u0x = sdot4(a,  x, u0x);  u0y = sdot4(a,  y, u0y);
            u1x = sdot4(b2, x, u1x);  u1y = sdot4(b2, y, u1y);
            xx  = sdot4(x,  x, xx);   yy  = sdot4(y,  y, yy);
            xy  = sdot4(x,  y, xy);
            xre = sdot4(x, r2, xre);  yre = sdot4(y, r2, yre);
        }
        p0[s] = u0h - u0t;
        p1[s] = u1h - u1t;
        sp[s] = hh + tt - 2*ht + 2*hre - 2*tre;
        n0[s] = u0x - u0y;
        n1[s] = u1x - u1y;
        sn[s] = xx + yy - 2*xy + 2*xre - 2*yre;
    }

    // 4-stage butterfly within the 16-lane group (exact int adds)
    #pragma unroll
    for (int off = 8; off > 0; off >>= 1) {
        #pragma unroll
        for (int s = 0; s < 2; ++s) {
            p0[s] += __shfl_xor(p0[s], off, 64);
            p1[s] += __shfl_xor(p1[s], off, 64);
            sp[s] += __shfl_xor(sp[s], off, 64);
            n0[s] += __shfl_xor(n0[s], off, 64);
            n1[s] += __shfl_xor(n1[s], off, 64);
            sn[s] += __shfl_xor(sn[s], off, 64);
        }
    }

    if (gl == 0) {
        #pragma unroll
        for (int s = 0; s < 2; ++s) {
            if (s == 1 && !has1) break;
            const float* par = par_buf + (size_t)rr[s] * PARW;
            const float s00 = par[0], s01 = par[1], s11 = par[2];
            const float u0re = par[3], u1re = par[4], rere = par[5];
            float P0 = (float)p0[s] * QS2 + u0re;
            float P1 = (float)p1[s] * QS2 + u1re;
            float SP = (float)sp[s] * QS2 + rere;
            float N0 = (float)n0[s] * QS2 + u0re;
            float N1 = (float)n1[s] * QS2 + u1re;
            float SN = (float)sn[s] * QS2 + rere;
            out[bs[s]]      = SP - (s00*P0*P0 + 2.f*s01*P0*P1 + s11*P1*P1);
            out[nB + bs[s]] = SN - (s00*N0*N0 + 2.f*s01*N0*N1 + s11*N1*N1);
        }
    }
}

extern "C" void kernel_launch(void* const* d_in, const int* in_sizes, int n_in,
                              void* d_out, int out_size, void* d_ws, size_t ws_size,
                              hipStream_t stream) {
    const int*   pos_h    = (const int*)  d_in[0];
    const int*   pos_t    = (const int*)  d_in[1];
    const int*   pos_r    = (const int*)  d_in[2];
    const int*   neg_h    = (const int*)  d_in[3];
    const int*   neg_t    = (const int*)  d_in[4];
    // d_in[5] = neg_r (unused by reference scores)
    const float* ent_emb  = (const float*)d_in[6];
    const float* heads    = (const float*)d_in[7];
    const float* bases    = (const float*)d_in[8];
    const int*   rel2head = (const int*)  d_in[9];
    const float* rel2mult = (const float*)d_in[10];
    float* out = (float*)d_out;

    const int nB = in_sizes[0];               // 65536
    const int R  = in_sizes[9];               // 1000
    const int E  = in_sizes[6] / D;           // 100000

    // ws layout: ent_q (E*256 B) | rel_q (R*768 B) | par (R*32 B)
    unsigned* ent_q   = (unsigned*)d_ws;
    unsigned* rel_q   = (unsigned*)((char*)d_ws + (size_t)E * 256);
    float*    par_buf = (float*)(rel_q + (size_t)R * RELQW);

    // merged prep: E quant waves + R rel waves
    {
        int waves = E + R;
        dim3 grid((waves + 3) / 4);
        transint_prep<<<grid, dim3(256), 0, stream>>>(
            ent_emb, heads, bases, rel2head, rel2mult,
            ent_q, rel_q, par_buf, E, R);
    }
    // main: 8 samples/wave, 32 per 256-thread block
    {
        dim3 grid((nB + 31) / 32);
        transint_main<<<grid, dim3(256), 0, stream>>>(
            pos_h, pos_t, pos_r, neg_h, neg_t,
            ent_q, rel_q, par_buf, out, nB);
    }
}